// Round 3
// baseline (872.804 us; speedup 1.0000x reference)
//
#include <hip/hip_runtime.h>
#include <stdint.h>

#define B_SZ 128
#define T_SZ 800
#define I_SZ 300
#define H_SZ 32
#define G_SZ 128   // 4*H
#define TW   80    // timesteps per window
#define NW   10    // windows
#define KP   328   // W_ih LDS stride (ushorts); data k<300, zeros 300..319
#define HP   84    // h_hist LDS stride (f32)
#define TP   804   // hT LDS stride (f32) in k_attn

typedef short bf16x8 __attribute__((ext_vector_type(8)));
typedef float f32x4 __attribute__((ext_vector_type(4)));

union Frag8 {
    bf16x8 v;
    ushort us[8];
    uint4  u4;
};

__device__ __forceinline__ ushort f2bf(float f) {
    unsigned int u = __float_as_uint(f);
    return (ushort)((u + 0x7fffu + ((u >> 16) & 1u)) >> 16);
}
__device__ __forceinline__ float sigmoidf_(float x) {
    return 1.f / (1.f + __expf(-x));
}
__device__ __forceinline__ float tanhfast(float x) {
    float ax = fabsf(x);
    float z = __expf(-2.f * ax);
    float r = (1.f - z) / (1.f + z);
    return copysignf(r, x);
}
__device__ __forceinline__ void pack8(Frag8& f, f32x4 a, f32x4 b) {
    f.us[0] = f2bf(a[0]); f.us[1] = f2bf(a[1]); f.us[2] = f2bf(a[2]); f.us[3] = f2bf(a[3]);
    f.us[4] = f2bf(b[0]); f.us[5] = f2bf(b[1]); f.us[6] = f2bf(b[2]); f.us[7] = f2bf(b[3]);
}

// ============ Kernel 1: fused gx-GEMM + LSTM scan. One block per batch b. ============
// Writes h (f32) transposed into the qk region of d_out: hT[b][h][t] at out + B_SZ + b*T*H.
__global__ __launch_bounds__(128) void k_lstm(
    const float* __restrict__ x, const float* __restrict__ W_ih,
    const float* __restrict__ W_hh,
    const float* __restrict__ b_ih, const float* __restrict__ b_hh,
    float* __restrict__ hT)
{
    const int b    = blockIdx.x;
    const int j    = threadIdx.x;      // gate index 0..127
    const int wave = j >> 6;
    const int lane = j & 63;
    const int m16  = lane & 15;
    const int quad = lane >> 4;

    __shared__ __align__(16) ushort Wlds[G_SZ][KP];    // 83968 B, bf16 W_ih, K zero-padded
    __shared__ __align__(16) float  gx_win[TW][132];   // 42240 B
    __shared__ __align__(16) float  h_hist[H_SZ][HP];  // 10752 B
    __shared__ __align__(16) float  h_cur[H_SZ];
    __shared__ __align__(16) float  act[G_SZ];

    // ---- convert W_ih (f32 -> bf16) into LDS once; zero-pad K 300..319 ----
    for (int idx = j; idx < G_SZ * I_SZ; idx += 128) {
        int r = idx / I_SZ, k = idx - r * I_SZ;
        Wlds[r][k] = f2bf(W_ih[idx]);
    }
    for (int idx = j; idx < G_SZ * 20; idx += 128) {
        int r = idx / 20, k = 300 + (idx - r * 20);
        Wlds[r][k] = 0;
    }

    // W_hh row j in f32 registers
    float W[H_SZ];
#pragma unroll
    for (int k = 0; k < H_SZ; ++k) W[k] = W_hh[j * H_SZ + k];

    float bias[8];
#pragma unroll
    for (int nt = 0; nt < 8; ++nt) {
        int col = nt * 16 + m16;
        bias[nt] = b_ih[col] + b_hh[col];
    }

    if (j < H_SZ) h_cur[j] = 0.f;
    float c = 0.f;
    __syncthreads();   // Wlds + h_cur ready

    const float* xb  = x + (size_t)b * T_SZ * I_SZ;
    float*       hTb = hT + (size_t)b * H_SZ * T_SZ;

    for (int w = 0; w < NW; ++w) {
        const int t0 = w * TW;

        // ---- MFMA: gx rows [t0, t0+80), cols [0,128). 5 row-tiles over 2 waves. ----
        for (int rt = wave; rt < TW / 16; rt += 2) {
            f32x4 acc[8];
#pragma unroll
            for (int nt = 0; nt < 8; ++nt) acc[nt] = (f32x4){0.f, 0.f, 0.f, 0.f};

            const float* xrow = xb + (size_t)(t0 + rt * 16 + m16) * I_SZ;

            // 9 full K-steps (k 0..287)
            for (int ks = 0; ks < 9; ++ks) {
                const int k0 = ks * 32;
                Frag8 a;
                f32x4 x0 = *(const f32x4*)(xrow + k0 + quad * 8);
                f32x4 x1 = *(const f32x4*)(xrow + k0 + quad * 8 + 4);
                pack8(a, x0, x1);
#pragma unroll
                for (int nt = 0; nt < 8; ++nt) {
                    Frag8 bf_;
                    bf_.u4 = *(const uint4*)&Wlds[nt * 16 + m16][k0 + quad * 8];
                    acc[nt] = __builtin_amdgcn_mfma_f32_16x16x32_bf16(a.v, bf_.v, acc[nt], 0, 0, 0);
                }
            }
            // tail K-step k0=288 (A predicated per element; B zero-padded in LDS)
            {
                const int k0 = 288;
                Frag8 a;
#pragma unroll
                for (int jj = 0; jj < 8; ++jj) {
                    int k = k0 + quad * 8 + jj;
                    a.us[jj] = (k < I_SZ) ? f2bf(xrow[k]) : (ushort)0;
                }
#pragma unroll
                for (int nt = 0; nt < 8; ++nt) {
                    Frag8 bf_;
                    bf_.u4 = *(const uint4*)&Wlds[nt * 16 + m16][k0 + quad * 8];
                    acc[nt] = __builtin_amdgcn_mfma_f32_16x16x32_bf16(a.v, bf_.v, acc[nt], 0, 0, 0);
                }
            }
            // C/D: row = quad*4 + r, col = m16
#pragma unroll
            for (int nt = 0; nt < 8; ++nt) {
#pragma unroll
                for (int r = 0; r < 4; ++r)
                    gx_win[rt * 16 + quad * 4 + r][nt * 16 + m16] = acc[nt][r] + bias[nt];
            }
        }
        __syncthreads();   // gx ready; also orders h_hist dump-reads vs rewrite

        // ---- serial scan over this window (pure f32) ----
        for (int tl = 0; tl < TW; ++tl) {
            float hreg[H_SZ];
#pragma unroll
            for (int k4 = 0; k4 < H_SZ / 4; ++k4) {
                f32x4 hv = *(const f32x4*)&h_cur[k4 * 4];   // broadcast read
                hreg[k4*4+0] = hv[0]; hreg[k4*4+1] = hv[1];
                hreg[k4*4+2] = hv[2]; hreg[k4*4+3] = hv[3];
            }
            float g = gx_win[tl][j];
#pragma unroll
            for (int k = 0; k < H_SZ; ++k) g += W[k] * hreg[k];
            // gate order i,f,g,o: only j in [64,96) uses tanh
            float a = (j >= 2 * H_SZ && j < 3 * H_SZ) ? tanhfast(g) : sigmoidf_(g);
            act[j] = a;
            __syncthreads();
            if (j < H_SZ) {
                float ig = act[j];
                float fg = act[H_SZ + j];
                float gg = act[2 * H_SZ + j];
                float og = act[3 * H_SZ + j];
                c = fg * c + ig * gg;
                float h = og * tanhfast(c);
                h_cur[j] = h;
                h_hist[j][tl] = h;
            }
            __syncthreads();
        }

        // ---- dump h_hist -> hT[b][h][t0:t0+80), f32, vectorized ----
        for (int idx = j; idx < H_SZ * (TW / 4); idx += 128) {
            int h   = idx / (TW / 4);
            int pos = idx - h * (TW / 4);
            *(f32x4*)(hTb + (size_t)h * T_SZ + t0 + pos * 4) = *(const f32x4*)&h_hist[h][pos * 4];
        }
        // next window's post-MFMA __syncthreads orders these reads vs h_hist rewrite
    }
}

// ============ Kernel 2: q = Ww@h, qk = h*q, out_fc = <qk,Wfc>. One block per b. ============
__global__ __launch_bounds__(256) void k_attn(
    const float* __restrict__ Ww, const float* __restrict__ bw,
    const float* __restrict__ Wfc, const float* __restrict__ bfc,
    float* __restrict__ out)
{
    const int b    = blockIdx.x;
    const int tid  = threadIdx.x;
    const int wave = tid >> 6;
    const int lane = tid & 63;
    const int m16  = lane & 15;
    const int quad = lane >> 4;

    __shared__ __align__(16) float hT_lds[H_SZ][TP];  // 102912 B
    __shared__ float red[4];

    float* region = out + B_SZ + (size_t)b * T_SZ * H_SZ;  // holds hT now, qk after

    // stage hT (f32) into LDS — ALL reads complete before any qk write
    for (int idx = tid; idx < H_SZ * (T_SZ / 4); idx += 256) {
        int h   = idx / (T_SZ / 4);
        int pos = idx - h * (T_SZ / 4);
        *(f32x4*)&hT_lds[h][pos * 4] = *(const f32x4*)(region + (size_t)h * T_SZ + pos * 4);
    }
    __syncthreads();

    float fc_acc = 0.f;

    for (int st = wave; st < T_SZ / 16; st += 4) {
        const int s0 = st * 16;
        f32x4 acc0 = (f32x4){0.f,0.f,0.f,0.f};
        f32x4 acc1 = (f32x4){0.f,0.f,0.f,0.f};
        const float* wwrow = Ww + (size_t)(s0 + m16) * T_SZ;

        for (int t0 = 0; t0 < T_SZ; t0 += 32) {
            Frag8 a, b0, b1;
            f32x4 w0 = *(const f32x4*)(wwrow + t0 + quad * 8);
            f32x4 w1 = *(const f32x4*)(wwrow + t0 + quad * 8 + 4);
            pack8(a, w0, w1);
            f32x4 h00 = *(const f32x4*)&hT_lds[m16][t0 + quad * 8];
            f32x4 h01 = *(const f32x4*)&hT_lds[m16][t0 + quad * 8 + 4];
            pack8(b0, h00, h01);
            f32x4 h10 = *(const f32x4*)&hT_lds[16 + m16][t0 + quad * 8];
            f32x4 h11 = *(const f32x4*)&hT_lds[16 + m16][t0 + quad * 8 + 4];
            pack8(b1, h10, h11);
            acc0 = __builtin_amdgcn_mfma_f32_16x16x32_bf16(a.v, b0.v, acc0, 0, 0, 0);
            acc1 = __builtin_amdgcn_mfma_f32_16x16x32_bf16(a.v, b1.v, acc1, 0, 0, 0);
        }
#pragma unroll
        for (int r = 0; r < 4; ++r) {
            int s = s0 + quad * 4 + r;
            float bws = bw[s];
            float q0 = acc0[r] + bws;
            float q1 = acc1[r] + bws;
            float h0 = hT_lds[m16][s];
            float h1 = hT_lds[16 + m16][s];
            float qk0 = h0 * q0;
            float qk1 = h1 * q1;
            region[(size_t)s * H_SZ + m16]      = qk0;
            region[(size_t)s * H_SZ + 16 + m16] = qk1;
            fc_acc += qk0 * Wfc[s * H_SZ + m16];
            fc_acc += qk1 * Wfc[s * H_SZ + 16 + m16];
        }
    }

#pragma unroll
    for (int off = 32; off > 0; off >>= 1)
        fc_acc += __shfl_down(fc_acc, off, 64);
    if (lane == 0) red[wave] = fc_acc;
    __syncthreads();
    if (tid == 0) out[b] = red[0] + red[1] + red[2] + red[3] + bfc[0];
}

extern "C" void kernel_launch(void* const* d_in, const int* in_sizes, int n_in,
                              void* d_out, int out_size, void* d_ws, size_t ws_size,
                              hipStream_t stream) {
    const float* x    = (const float*)d_in[0];
    const float* W_ih = (const float*)d_in[1];
    const float* W_hh = (const float*)d_in[2];
    const float* b_ih = (const float*)d_in[3];
    const float* b_hh = (const float*)d_in[4];
    const float* Ww   = (const float*)d_in[5];
    const float* bw   = (const float*)d_in[6];
    const float* Wfc  = (const float*)d_in[7];
    const float* bfc  = (const float*)d_in[8];

    float* out = (float*)d_out;
    float* hT  = out + B_SZ;   // qk region doubles as hT scratch (same element count)

    k_lstm<<<B_SZ, 128, 0, stream>>>(x, W_ih, W_hh, b_ih, b_hh, hT);
    k_attn<<<B_SZ, 256, 0, stream>>>(Ww, bw, Wfc, bfc, out);
}

// Round 4
// 833.363 us; speedup vs baseline: 1.0473x; 1.0473x over previous
//
#include <hip/hip_runtime.h>
#include <hip/hip_bf16.h>
#include <stdint.h>

#define B_SZ 128
#define T_SZ 800
#define I_SZ 300
#define H_SZ 32
#define G_SZ 128   // 4*H
#define TW   80    // timesteps per window
#define NW   10    // windows
#define KP   328   // W_ih LDS stride (ushorts); data k<300, zeros 300..319
#define GXP  132   // gx_win stride (f32)
#define TP   808   // hT LDS stride (ushorts) in k_attn

typedef short bf16x8 __attribute__((ext_vector_type(8)));
typedef float f32x4 __attribute__((ext_vector_type(4)));

union Frag8 {
    bf16x8 v;
    ushort us[8];
    uint4  u4;
};

__device__ __forceinline__ float bf2f(ushort u) {
    return __uint_as_float(((unsigned int)u) << 16);
}
__device__ __forceinline__ ushort f2bf(float f) {
    unsigned int u = __float_as_uint(f);
    return (ushort)((u + 0x7fffu + ((u >> 16) & 1u)) >> 16);
}
// packed f32x8 -> bf16x8 via v_cvt_pk_bf16_f32
__device__ __forceinline__ bf16x8 pack8pk(f32x4 a, f32x4 b) {
    union { bf16x8 v; __hip_bfloat162 h[4]; } u;
    u.h[0] = __float22bfloat162_rn(make_float2(a[0], a[1]));
    u.h[1] = __float22bfloat162_rn(make_float2(a[2], a[3]));
    u.h[2] = __float22bfloat162_rn(make_float2(b[0], b[1]));
    u.h[3] = __float22bfloat162_rn(make_float2(b[2], b[3]));
    return u.v;
}
__device__ __forceinline__ uint cvt2(float a, float b) {
    union { __hip_bfloat162 h; uint u; } x;
    x.h = __float22bfloat162_rn(make_float2(a, b));
    return x.u;
}
// tanh via exp(-2|x|); 1 transcendental + 1 rcp
__device__ __forceinline__ float tanhfast(float x) {
    float ax = fabsf(x);
    float z = __expf(-2.f * ax);
    float r = (1.f - z) / (1.f + z);
    return copysignf(r, x);
}

// ============ Kernel 1: fused gx-GEMM + LSTM scan. ONE WAVE per batch b. ============
// No __syncthreads anywhere: single wave, in-order DS pipe.
// Lane l owns gates l and l+64. Writes h as bf16 into the first half of the
// qk region of d_out: hT[b][h][t] (ushort) at (ushort*)(out + B_SZ + b*25600).
__global__ __launch_bounds__(64) void k_lstm(
    const float* __restrict__ x, const float* __restrict__ W_ih,
    const float* __restrict__ W_hh,
    const float* __restrict__ b_ih, const float* __restrict__ b_hh,
    float* __restrict__ out)
{
    const int b    = blockIdx.x;
    const int l    = threadIdx.x;      // 0..63
    const int m16  = l & 15;
    const int quad = l >> 4;

    __shared__ __align__(16) ushort Wlds[G_SZ][KP];     // 83968 B  (bf16 W_ih, K zero-padded)
    __shared__ __align__(16) float  gx_win[TW][GXP];    // 42240 B
    __shared__ __align__(16) float  h_cur[H_SZ];

    // ---- stage W_ih f32 -> bf16 LDS (pairs; 300 even so pairs never straddle rows) ----
    for (int f = l; f < G_SZ * I_SZ / 2; f += 64) {
        int r = f / (I_SZ / 2);
        int k = 2 * (f - r * (I_SZ / 2));
        float2 w = *(const float2*)(W_ih + (size_t)r * I_SZ + k);
        *(uint*)&Wlds[r][k] = cvt2(w.x, w.y);
    }
    for (int idx = l; idx < G_SZ * 10; idx += 64) {       // zero-pad k 300..319
        int r = idx / 10, kk = 300 + 2 * (idx - r * 10);
        *(uint*)&Wlds[r][kk] = 0u;
    }

    // W_hh rows l and l+64 in registers (f32)
    float W0[H_SZ], W1[H_SZ];
#pragma unroll
    for (int k = 0; k < H_SZ; ++k) W0[k] = W_hh[l * H_SZ + k];
#pragma unroll
    for (int k = 0; k < H_SZ; ++k) W1[k] = W_hh[(l + 64) * H_SZ + k];

    float bias[8];
#pragma unroll
    for (int nt = 0; nt < 8; ++nt) {
        int col = nt * 16 + m16;
        bias[nt] = b_ih[col] + b_hh[col];
    }

    if (l < H_SZ) h_cur[l] = 0.f;
    float c = 0.f;

    const float* xb = x + (size_t)b * T_SZ * I_SZ;
    ushort* hTb = (ushort*)(out + B_SZ + (size_t)b * T_SZ * H_SZ);  // bf16, [h][t]

    for (int w = 0; w < NW; ++w) {
        const int t0 = w * TW;

        // ---- MFMA: gx rows [t0,t0+80), cols [0,128). 5 row-tiles, single wave. ----
        for (int rt = 0; rt < TW / 16; ++rt) {
            f32x4 acc[8];
#pragma unroll
            for (int nt = 0; nt < 8; ++nt) acc[nt] = (f32x4){0.f, 0.f, 0.f, 0.f};

            const float* xrow = xb + (size_t)(t0 + rt * 16 + m16) * I_SZ;

            for (int ks = 0; ks < 9; ++ks) {      // k 0..287
                const int k0 = ks * 32;
                f32x4 x0 = *(const f32x4*)(xrow + k0 + quad * 8);
                f32x4 x1 = *(const f32x4*)(xrow + k0 + quad * 8 + 4);
                bf16x8 a = pack8pk(x0, x1);
#pragma unroll
                for (int nt = 0; nt < 8; ++nt) {
                    Frag8 bf_;
                    bf_.u4 = *(const uint4*)&Wlds[nt * 16 + m16][k0 + quad * 8];
                    acc[nt] = __builtin_amdgcn_mfma_f32_16x16x32_bf16(a, bf_.v, acc[nt], 0, 0, 0);
                }
            }
            {   // tail k0=288 (A predicated; B zero-padded in LDS)
                const int k0 = 288;
                Frag8 a;
#pragma unroll
                for (int jj = 0; jj < 8; ++jj) {
                    int k = k0 + quad * 8 + jj;
                    a.us[jj] = (k < I_SZ) ? f2bf(xrow[k]) : (ushort)0;
                }
#pragma unroll
                for (int nt = 0; nt < 8; ++nt) {
                    Frag8 bf_;
                    bf_.u4 = *(const uint4*)&Wlds[nt * 16 + m16][k0 + quad * 8];
                    acc[nt] = __builtin_amdgcn_mfma_f32_16x16x32_bf16(a.v, bf_.v, acc[nt], 0, 0, 0);
                }
            }
            // C/D: row = quad*4 + r, col = m16
#pragma unroll
            for (int nt = 0; nt < 8; ++nt) {
#pragma unroll
                for (int r = 0; r < 4; ++r)
                    gx_win[rt * 16 + quad * 4 + r][nt * 16 + m16] = acc[nt][r] + bias[nt];
            }
        }

        // ---- serial scan over this window: no barriers, wave-internal ordering ----
        for (int tl8 = 0; tl8 < TW; tl8 += 8) {
            union { ushort u[8]; uint4 v; } hbuf;
#pragma unroll
            for (int uu = 0; uu < 8; ++uu) {
                const int tl = tl8 + uu;
                // load h (broadcast, conflict-free) and gx for both gates
                float hr[H_SZ];
#pragma unroll
                for (int k4 = 0; k4 < H_SZ / 4; ++k4) {
                    f32x4 hv = *(const f32x4*)&h_cur[k4 * 4];
                    hr[k4*4+0] = hv[0]; hr[k4*4+1] = hv[1];
                    hr[k4*4+2] = hv[2]; hr[k4*4+3] = hv[3];
                }
                float g0 = gx_win[tl][l];
                float g1 = gx_win[tl][l + 64];
                float s00=0.f,s01=0.f,s02=0.f,s03=0.f;
                float s10=0.f,s11=0.f,s12=0.f,s13=0.f;
#pragma unroll
                for (int k = 0; k < H_SZ; k += 4) {
                    s00 += W0[k+0]*hr[k+0]; s01 += W0[k+1]*hr[k+1];
                    s02 += W0[k+2]*hr[k+2]; s03 += W0[k+3]*hr[k+3];
                    s10 += W1[k+0]*hr[k+0]; s11 += W1[k+1]*hr[k+1];
                    s12 += W1[k+2]*hr[k+2]; s13 += W1[k+3]*hr[k+3];
                }
                g0 += (s00 + s01) + (s02 + s03);
                g1 += (s10 + s11) + (s12 + s13);

                // gate l: i (l<32) or f (l>=32) -> always sigmoid, via tanh(x/2)
                float a0 = 0.5f * tanhfast(0.5f * g0) + 0.5f;
                // gate l+64: g (tanh) for l<32, o (sigmoid) for l>=32 — branchless
                float z1 = (l < H_SZ) ? g1 : 0.5f * g1;
                float t1 = tanhfast(z1);
                float a1 = (l < H_SZ) ? t1 : 0.5f * t1 + 0.5f;

                float fg = __shfl_down(a0, 32);   // f_gate(l) from lane l+32
                float og = __shfl_down(a1, 32);   // o_gate(l) from lane l+32
                // lanes >=32 compute garbage below; they never store
                c = fg * c + a0 * a1;             // c = f*c + i*g
                float h = og * tanhfast(c);
                if (l < H_SZ) h_cur[l] = h;
                hbuf.u[uu] = f2bf(h);
            }
            if (l < H_SZ)
                *(uint4*)(hTb + (size_t)l * T_SZ + t0 + tl8) = hbuf.v;
        }
    }
}

// ============ Kernel 2: q = Ww@h, qk = h*q, out_fc = <qk,Wfc>. One block per b. ============
// hT (bf16) lives in the first half of this block's own qk region -> stage to
// LDS, barrier, then overwrite region with qk (f32). 256 threads = 4 waves.
__global__ __launch_bounds__(256) void k_attn(
    const float* __restrict__ Ww, const float* __restrict__ bw,
    const float* __restrict__ Wfc, const float* __restrict__ bfc,
    float* __restrict__ out)
{
    const int b    = blockIdx.x;
    const int tid  = threadIdx.x;
    const int wave = tid >> 6;
    const int lane = tid & 63;
    const int m16  = lane & 15;
    const int quad = lane >> 4;

    __shared__ __align__(16) ushort hT_lds[H_SZ][TP];  // 51712 B
    __shared__ float red[4];

    float*  region = out + B_SZ + (size_t)b * T_SZ * H_SZ;  // qk region (f32)
    ushort* hTg    = (ushort*)region;                        // bf16 hT in first half

    // stage hT into LDS; ALL reads complete before any qk write
    for (int idx = tid; idx < H_SZ * (T_SZ / 8); idx += 256) {
        int h   = idx / (T_SZ / 8);
        int pos = idx - h * (T_SZ / 8);
        uint4 v = *(const uint4*)(hTg + (size_t)h * T_SZ + pos * 8);
        *(uint4*)&hT_lds[h][pos * 8] = v;
    }
    __syncthreads();

    float fc_acc = 0.f;

    for (int st = wave; st < T_SZ / 16; st += 4) {
        const int s0 = st * 16;
        f32x4 acc0 = (f32x4){0.f,0.f,0.f,0.f};
        f32x4 acc1 = (f32x4){0.f,0.f,0.f,0.f};
        const float* wwrow = Ww + (size_t)(s0 + m16) * T_SZ;

        for (int t0 = 0; t0 < T_SZ; t0 += 32) {
            f32x4 w0 = *(const f32x4*)(wwrow + t0 + quad * 8);
            f32x4 w1 = *(const f32x4*)(wwrow + t0 + quad * 8 + 4);
            bf16x8 a = pack8pk(w0, w1);
            Frag8 b0, b1;
            b0.u4 = *(const uint4*)&hT_lds[m16][t0 + quad * 8];
            b1.u4 = *(const uint4*)&hT_lds[16 + m16][t0 + quad * 8];
            acc0 = __builtin_amdgcn_mfma_f32_16x16x32_bf16(a, b0.v, acc0, 0, 0, 0);
            acc1 = __builtin_amdgcn_mfma_f32_16x16x32_bf16(a, b1.v, acc1, 0, 0, 0);
        }
#pragma unroll
        for (int r = 0; r < 4; ++r) {
            int s = s0 + quad * 4 + r;
            float bws = bw[s];
            float q0 = acc0[r] + bws;
            float q1 = acc1[r] + bws;
            float h0 = bf2f(hT_lds[m16][s]);
            float h1 = bf2f(hT_lds[16 + m16][s]);
            float qk0 = h0 * q0;
            float qk1 = h1 * q1;
            region[(size_t)s * H_SZ + m16]      = qk0;
            region[(size_t)s * H_SZ + 16 + m16] = qk1;
            fc_acc += qk0 * Wfc[s * H_SZ + m16];
            fc_acc += qk1 * Wfc[s * H_SZ + 16 + m16];
        }
    }

#pragma unroll
    for (int off = 32; off > 0; off >>= 1)
        fc_acc += __shfl_down(fc_acc, off, 64);
    if (lane == 0) red[wave] = fc_acc;
    __syncthreads();
    if (tid == 0) out[b] = red[0] + red[1] + red[2] + red[3] + bfc[0];
}

extern "C" void kernel_launch(void* const* d_in, const int* in_sizes, int n_in,
                              void* d_out, int out_size, void* d_ws, size_t ws_size,
                              hipStream_t stream) {
    const float* x    = (const float*)d_in[0];
    const float* W_ih = (const float*)d_in[1];
    const float* W_hh = (const float*)d_in[2];
    const float* b_ih = (const float*)d_in[3];
    const float* b_hh = (const float*)d_in[4];
    const float* Ww   = (const float*)d_in[5];
    const float* bw   = (const float*)d_in[6];
    const float* Wfc  = (const float*)d_in[7];
    const float* bfc  = (const float*)d_in[8];

    float* out = (float*)d_out;

    k_lstm<<<B_SZ, 64, 0, stream>>>(x, W_ih, W_hh, b_ih, b_hh, out);
    k_attn<<<B_SZ, 256, 0, stream>>>(Ww, bw, Wfc, bfc, out);
}

// Round 5
// 668.046 us; speedup vs baseline: 1.3065x; 1.2475x over previous
//
#include <hip/hip_runtime.h>
#include <hip/hip_bf16.h>
#include <stdint.h>

#define B_SZ 128
#define T_SZ 800
#define I_SZ 300
#define H_SZ 32
#define G_SZ 128   // 4*H
#define TP   808   // h_lds stride (ushorts), 16B-aligned rows

typedef short bf16x8 __attribute__((ext_vector_type(8)));
typedef float f32x4 __attribute__((ext_vector_type(4)));

union Frag8 { bf16x8 v; ushort us[8]; uint4 u4; };

__device__ __forceinline__ float bf2f(ushort u) {
    return __uint_as_float(((unsigned int)u) << 16);
}
__device__ __forceinline__ ushort f2bf(float f) {
    unsigned int u = __float_as_uint(f);
    return (ushort)((u + 0x7fffu + ((u >> 16) & 1u)) >> 16);
}
// packed f32x8 -> bf16x8 via v_cvt_pk_bf16_f32
__device__ __forceinline__ bf16x8 pack8pk(f32x4 a, f32x4 b) {
    union { bf16x8 v; __hip_bfloat162 h[4]; } u;
    u.h[0] = __float22bfloat162_rn(make_float2(a[0], a[1]));
    u.h[1] = __float22bfloat162_rn(make_float2(a[2], a[3]));
    u.h[2] = __float22bfloat162_rn(make_float2(b[0], b[1]));
    u.h[3] = __float22bfloat162_rn(make_float2(b[2], b[3]));
    return u.v;
}
__device__ __forceinline__ float tanhfast(float x) {
    float ax = fabsf(x);
    float z = __expf(-2.f * ax);
    float r = (1.f - z) / (1.f + z);
    return copysignf(r, x);
}
__device__ __forceinline__ float rdlane(float v, int srclane) {
    return __int_as_float(__builtin_amdgcn_readlane(__float_as_int(v), srclane));
}

// ============ Kernel 1: gx GEMM. gxp[row][g] = pack_f16(gate g, gate g+64). ============
// M = B*T = 102400 rows (64/block, 4 waves x 16), K = 300, N = 128.
__global__ __launch_bounds__(256) void k_gx(
    const float* __restrict__ x, const float* __restrict__ W_ih,
    const float* __restrict__ b_ih, const float* __restrict__ b_hh,
    uint* __restrict__ gxp)
{
    const int wave = threadIdx.x >> 6;
    const int lane = threadIdx.x & 63;
    const int m16  = lane & 15;
    const int quad = lane >> 4;
    const int row0 = blockIdx.x * 64 + wave * 16;

    f32x4 acc[8];
#pragma unroll
    for (int nt = 0; nt < 8; ++nt) acc[nt] = (f32x4){0.f, 0.f, 0.f, 0.f};

    float bias[8];
#pragma unroll
    for (int nt = 0; nt < 8; ++nt) {
        int col = nt * 16 + m16;
        bias[nt] = b_ih[col] + b_hh[col];
    }

    const float* xrow = x + (size_t)(row0 + m16) * I_SZ;

    for (int ks = 0; ks < 9; ++ks) {          // k = 0..287
        const int k0 = ks * 32;
        f32x4 x0 = *(const f32x4*)(xrow + k0 + quad * 8);
        f32x4 x1 = *(const f32x4*)(xrow + k0 + quad * 8 + 4);
        bf16x8 a = pack8pk(x0, x1);
#pragma unroll
        for (int nt = 0; nt < 8; ++nt) {
            const float* brow = W_ih + (size_t)(nt * 16 + m16) * I_SZ + k0 + quad * 8;
            f32x4 w0 = *(const f32x4*)brow;
            f32x4 w1 = *(const f32x4*)(brow + 4);
            bf16x8 bb = pack8pk(w0, w1);
            acc[nt] = __builtin_amdgcn_mfma_f32_16x16x32_bf16(a, bb, acc[nt], 0, 0, 0);
        }
    }
    {   // tail k0 = 288..299 (predicated scalar, bf16-converted)
        const int k0 = 288;
        Frag8 a;
#pragma unroll
        for (int jj = 0; jj < 8; ++jj) {
            int k = k0 + quad * 8 + jj;
            a.us[jj] = (k < I_SZ) ? f2bf(xrow[k]) : (ushort)0;
        }
#pragma unroll
        for (int nt = 0; nt < 8; ++nt) {
            const float* brow = W_ih + (size_t)(nt * 16 + m16) * I_SZ;
            Frag8 bb;
#pragma unroll
            for (int jj = 0; jj < 8; ++jj) {
                int k = k0 + quad * 8 + jj;
                bb.us[jj] = (k < I_SZ) ? f2bf(brow[k]) : (ushort)0;
            }
            acc[nt] = __builtin_amdgcn_mfma_f32_16x16x32_bf16(a.v, bb.v, acc[nt], 0, 0, 0);
        }
    }
    // C/D: row = quad*4 + r, col = m16. Pack (col, col+64) as f16 pair -> one uint.
#pragma unroll
    for (int nt = 0; nt < 4; ++nt) {
#pragma unroll
        for (int r = 0; r < 4; ++r) {
            int row = row0 + quad * 4 + r;
            union { uint u; _Float16 h[2]; } pk;
            pk.h[0] = (_Float16)(acc[nt][r]     + bias[nt]);
            pk.h[1] = (_Float16)(acc[nt + 4][r] + bias[nt + 4]);
            gxp[(size_t)row * 64 + nt * 16 + m16] = pk.u;
        }
    }
}

// ============ Kernel 2: convert Ww f32 -> bf16 (one-shot) ============
__global__ __launch_bounds__(256) void k_cvt(
    const float* __restrict__ Ww, uint* __restrict__ WwB)
{
    int i = blockIdx.x * 256 + threadIdx.x;    // one bf16 pair per thread
    if (i < T_SZ * T_SZ / 2) {
        float2 w = ((const float2*)Ww)[i];
        WwB[i] = ((uint)f2bf(w.y) << 16) | (uint)f2bf(w.x);
    }
}

// ============ Kernel 3: LSTM scan (wave 0) + attention (all 4 waves). One block / b. ============
// Scan: lane l holds gates l (i for l<32, f for l>=32) and l+64 (g for l<32, o for l>=32).
// c,h live on lanes 32..63 (unit = lane-32). h broadcast via v_readlane (no LDS, no DS pipe).
// gx arrives via an 8-deep register prefetch ring (1 coalesced uint/lane/step).
// h written bf16 into LDS; after one barrier all 4 waves run the q-MFMA + qk + fc epilogue.
__global__ __launch_bounds__(256) void k_main(
    const uint* __restrict__ gxp, const float* __restrict__ W_hh,
    const uint* __restrict__ WwB, const float* __restrict__ bw,
    const float* __restrict__ Wfc, const float* __restrict__ bfc,
    float* __restrict__ out)
{
    const int b    = blockIdx.x;
    const int tid  = threadIdx.x;
    const int wave = tid >> 6;
    const int lane = tid & 63;
    const int m16  = lane & 15;
    const int quad = lane >> 4;

    __shared__ __align__(16) ushort h_lds[H_SZ][TP];   // 51712 B, bf16 h[unit][t]
    __shared__ float red[4];

    if (wave == 0) {
        // ---- W_hh rows lane and lane+64 in f32 registers ----
        float W0[H_SZ], W1[H_SZ];
#pragma unroll
        for (int k = 0; k < H_SZ; ++k) W0[k] = W_hh[lane * H_SZ + k];
#pragma unroll
        for (int k = 0; k < H_SZ; ++k) W1[k] = W_hh[(lane + 64) * H_SZ + k];

        const uint* gb = gxp + (size_t)b * T_SZ * 64;
        uint G[8];
#pragma unroll
        for (int uu = 0; uu < 8; ++uu) G[uu] = gb[uu * 64 + lane];

        float hval = 0.f, c = 0.f;

        for (int t8 = 0; t8 < T_SZ; t8 += 8) {
#pragma unroll
            for (int uu = 0; uu < 8; ++uu) {
                const int t = t8 + uu;
                uint gpk = G[uu];
                int tn = t + 8; tn = (tn < T_SZ) ? tn : (T_SZ - 1);
                G[uu] = gb[(size_t)tn * 64 + lane];        // prefetch, 8 steps ahead

                union { uint u; _Float16 h[2]; } gq; gq.u = gpk;
                float s00 = (float)gq.h[0], s01 = 0.f, s02 = 0.f, s03 = 0.f;
                float s10 = (float)gq.h[1], s11 = 0.f, s12 = 0.f, s13 = 0.f;
#pragma unroll
                for (int k = 0; k < H_SZ; k += 4) {
                    float h0 = rdlane(hval, 32 + k);
                    float h1 = rdlane(hval, 33 + k);
                    float h2 = rdlane(hval, 34 + k);
                    float h3 = rdlane(hval, 35 + k);
                    s00 += h0 * W0[k];     s10 += h0 * W1[k];
                    s01 += h1 * W0[k + 1]; s11 += h1 * W1[k + 1];
                    s02 += h2 * W0[k + 2]; s12 += h2 * W1[k + 2];
                    s03 += h3 * W0[k + 3]; s13 += h3 * W1[k + 3];
                }
                float g0 = (s00 + s01) + (s02 + s03);      // i (l<32) / f (l>=32)
                float g1 = (s10 + s11) + (s12 + s13);      // g (l<32) / o (l>=32)

                float a0 = 0.5f * tanhfast(0.5f * g0) + 0.5f;   // sigmoid
                float z1 = (lane < H_SZ) ? g1 : 0.5f * g1;
                float t1 = tanhfast(z1);
                float a1 = (lane < H_SZ) ? t1 : 0.5f * t1 + 0.5f;  // tanh / sigmoid

                float ig  = a0 * a1;                // lanes<32: i*g
                float igs = __shfl_up(ig, 32, 64);  // lanes>=32 receive i*g
                c = a0 * c + igs;                   // f*c + i*g   (lanes>=32)
                hval = a1 * tanhfast(c);            // o*tanh(c)   (lanes>=32)
                if (lane >= H_SZ) h_lds[lane - H_SZ][t] = f2bf(hval);
            }
        }
    }
    __syncthreads();   // h_lds complete; waves 1-3 were parked here

    // ---- attention: q = Ww @ h, qk = h*q, fc = <qk, Wfc>. 4 waves, 50 s-tiles. ----
    float* region = out + B_SZ + (size_t)b * T_SZ * H_SZ;   // qk (f32)
    float fc_acc = 0.f;

    for (int st = wave; st < T_SZ / 16; st += 4) {
        const int s0 = st * 16;
        f32x4 acc0 = (f32x4){0.f,0.f,0.f,0.f};
        f32x4 acc1 = (f32x4){0.f,0.f,0.f,0.f};
        const ushort* wwrow = (const ushort*)WwB + (size_t)(s0 + m16) * T_SZ;

        for (int t0 = 0; t0 < T_SZ; t0 += 32) {
            Frag8 a, b0, b1;
            a.u4  = *(const uint4*)(wwrow + t0 + quad * 8);
            b0.u4 = *(const uint4*)&h_lds[m16][t0 + quad * 8];
            b1.u4 = *(const uint4*)&h_lds[16 + m16][t0 + quad * 8];
            acc0 = __builtin_amdgcn_mfma_f32_16x16x32_bf16(a.v, b0.v, acc0, 0, 0, 0);
            acc1 = __builtin_amdgcn_mfma_f32_16x16x32_bf16(a.v, b1.v, acc1, 0, 0, 0);
        }
#pragma unroll
        for (int r = 0; r < 4; ++r) {
            int s = s0 + quad * 4 + r;
            float bws = bw[s];
            float q0 = acc0[r] + bws;
            float q1 = acc1[r] + bws;
            float h0 = bf2f(h_lds[m16][s]);
            float h1 = bf2f(h_lds[16 + m16][s]);
            float qk0 = h0 * q0;
            float qk1 = h1 * q1;
            region[(size_t)s * H_SZ + m16]      = qk0;
            region[(size_t)s * H_SZ + 16 + m16] = qk1;
            fc_acc += qk0 * Wfc[s * H_SZ + m16];
            fc_acc += qk1 * Wfc[s * H_SZ + 16 + m16];
        }
    }

#pragma unroll
    for (int off = 32; off > 0; off >>= 1)
        fc_acc += __shfl_down(fc_acc, off, 64);
    if (lane == 0) red[wave] = fc_acc;
    __syncthreads();
    if (tid == 0) out[b] = red[0] + red[1] + red[2] + red[3] + bfc[0];
}

extern "C" void kernel_launch(void* const* d_in, const int* in_sizes, int n_in,
                              void* d_out, int out_size, void* d_ws, size_t ws_size,
                              hipStream_t stream) {
    const float* x    = (const float*)d_in[0];
    const float* W_ih = (const float*)d_in[1];
    const float* W_hh = (const float*)d_in[2];
    const float* b_ih = (const float*)d_in[3];
    const float* b_hh = (const float*)d_in[4];
    const float* Ww   = (const float*)d_in[5];
    const float* bw   = (const float*)d_in[6];
    const float* Wfc  = (const float*)d_in[7];
    const float* bfc  = (const float*)d_in[8];

    float* out = (float*)d_out;

    // ws layout: gxp (f16 pairs) 102400*64*4 = 26,214,400 B ; WwB bf16 800*800*2 = 1,280,000 B
    uint* gxp = (uint*)d_ws;
    uint* WwB = (uint*)((char*)d_ws + (size_t)102400 * 64 * 4);

    k_cvt <<<1250, 256, 0, stream>>>(Ww, WwB);
    k_gx  <<<1600, 256, 0, stream>>>(x, W_ih, b_ih, b_hh, gxp);
    k_main<<<B_SZ, 256, 0, stream>>>(gxp, W_hh, WwB, bw, Wfc, bfc, out);
}

// Round 7
// 536.494 us; speedup vs baseline: 1.6269x; 1.2452x over previous
//
#include <hip/hip_runtime.h>
#include <stdint.h>

#define B_SZ 128
#define T_SZ 800
#define I_SZ 300
#define KPAD 320     // W_ih K padded with zeros to 320
#define H_SZ 32
#define G_SZ 128
#define NWIN 50      // 800 / 16
#define NBUF 4       // gx window buffers
#define TP   808     // hist stride (f16 elems): 16B-aligned rows

typedef float f32x4 __attribute__((ext_vector_type(4)));
typedef _Float16 half8 __attribute__((ext_vector_type(8)));

union FragH { half8 v; _Float16 h[8]; uint4 u4; };
union PkU  { uint u; _Float16 h[2]; };
union HsU  { ushort s; _Float16 h; };

__device__ __forceinline__ float tanhfast(float x) {
    float ax = fabsf(x);
    float z = __expf(-2.f * ax);
    float r = __fdividef(1.f - z, 1.f + z);
    return __builtin_copysignf(r, x);
}
__device__ __forceinline__ float sigmoidf_(float x) {
    return __fdividef(1.f, 1.f + __expf(-x));
}

// ============ k_prep: W_ih f32 -> f16 (K zero-padded to 320); Ww f32 -> f16 ============
__global__ __launch_bounds__(256) void k_prep(
    const float* __restrict__ W_ih, const float* __restrict__ Ww,
    _Float16* __restrict__ W_ihH, _Float16* __restrict__ WwH)
{
    int i = blockIdx.x * 256 + threadIdx.x;
    if (i < G_SZ * KPAD) {
        int r = i / KPAD, k = i - r * KPAD;
        W_ihH[i] = (k < I_SZ) ? (_Float16)W_ih[r * I_SZ + k] : (_Float16)0.f;
    }
    int j = i - G_SZ * KPAD;
    if (j >= 0 && j < T_SZ * T_SZ) WwH[j] = (_Float16)Ww[j];
}

// ============ k_main: producer waves (gx MFMA) + consumer wave (f32 scan) + attention ============
// Wave 0 = consumer (LSTM scan, f32 recurrence). Lane l owns gates l (i/f) and l+64 (g/o);
// c,h live on lanes 32..63 (unit = lane-32). h(t) broadcast via 128-B f32 LDS ring —
// in-order DS pipe within the wave, no barrier. Recurrence numerics == R5 (f32 W_hh, f32 h).
// Waves 1..3 = producers: every 3rd 16-step gx window via f16 MFMA -> gxbuf (f16 pairs),
// handshake via LDS acquire/release counters. Then one barrier; all 4 waves run attention.
__global__ __launch_bounds__(256) void k_main(
    const float* __restrict__ x, const _Float16* __restrict__ W_ihH,
    const float* __restrict__ W_hh,
    const float* __restrict__ b_ih, const float* __restrict__ b_hh,
    const _Float16* __restrict__ WwH, const float* __restrict__ bw,
    const float* __restrict__ Wfc, const float* __restrict__ bfc,
    float* __restrict__ out)
{
    const int b    = blockIdx.x;
    const int tid  = threadIdx.x;
    const int wave = tid >> 6;
    const int lane = tid & 63;
    const int m16  = lane & 15;
    const int quad = lane >> 4;

    __shared__ __align__(16) ushort hist[H_SZ][TP];      // 51712 B, f16 h[unit][t]
    __shared__ __align__(16) uint   gxbuf[NBUF][16][64]; // 16384 B, (gate l, gate l+64) f16 pairs
    __shared__ __align__(16) float  ringf[2][H_SZ];      // 256 B, h(t) f32 broadcast
    __shared__ int produced, consumed;
    __shared__ float red[4];

    if (tid == 0) { produced = 0; consumed = 0; }
    __syncthreads();

    if (wave == 0) {
        // ---------------- consumer: LSTM scan (f32 recurrence) ----------------
        float W0[H_SZ], W1[H_SZ];           // W_hh rows lane, lane+64 (f32)
#pragma unroll
        for (int k = 0; k < H_SZ; ++k) W0[k] = W_hh[lane * H_SZ + k];
#pragma unroll
        for (int k = 0; k < H_SZ; ++k) W1[k] = W_hh[(lane + 64) * H_SZ + k];

        if (lane >= H_SZ) ringf[1][lane - H_SZ] = 0.f;   // h(-1)=0; step 0 reads buf 1
        float c = 0.f;

        for (int w = 0; w < NWIN; ++w) {
            while (__atomic_load_n(&produced, __ATOMIC_ACQUIRE) < w + 1)
                __builtin_amdgcn_s_sleep(2);
#pragma unroll 4
            for (int tl = 0; tl < 16; ++tl) {
                const int t = w * 16 + tl;
                PkU g; g.u = gxbuf[w & (NBUF - 1)][tl][lane];   // used late (acc-add)
                const int rb = (t + 1) & 1;                     // buffer holding h(t-1)
                float hr[H_SZ];
#pragma unroll
                for (int k4 = 0; k4 < H_SZ / 4; ++k4) {
                    f32x4 hv = *(const f32x4*)&ringf[rb][k4 * 4];  // broadcast b128
                    hr[k4*4+0] = hv[0]; hr[k4*4+1] = hv[1];
                    hr[k4*4+2] = hv[2]; hr[k4*4+3] = hv[3];
                }
                float p0=0.f,p1=0.f,p2=0.f,p3=0.f;
                float q0=0.f,q1=0.f,q2=0.f,q3=0.f;
#pragma unroll
                for (int k = 0; k < H_SZ; k += 4) {
                    p0 += W0[k+0]*hr[k+0]; q0 += W1[k+0]*hr[k+0];
                    p1 += W0[k+1]*hr[k+1]; q1 += W1[k+1]*hr[k+1];
                    p2 += W0[k+2]*hr[k+2]; q2 += W1[k+2]*hr[k+2];
                    p3 += W0[k+3]*hr[k+3]; q3 += W1[k+3]*hr[k+3];
                }
                float g0 = ((p0 + p1) + (p2 + p3)) + (float)g.h[0];  // i / f
                float g1 = ((q0 + q1) + (q2 + q3)) + (float)g.h[1];  // g / o

                float a0 = sigmoidf_(g0);
                float zz = (lane < H_SZ) ? g1 : 0.5f * g1;
                float th = tanhfast(zz);
                float a1 = (lane < H_SZ) ? th : 0.5f * th + 0.5f;

                float ig  = a0 * a1;                   // i*g on lanes<32
                float igs = __shfl_up(ig, 32, 64);     // deliver to lanes>=32
                c = a0 * c + igs;                      // f*c + i*g   (lanes>=32 valid)
                float h = a1 * tanhfast(c);            // o*tanh(c)
                if (lane >= H_SZ) {
                    ringf[t & 1][lane - H_SZ] = h;     // f32 feedback (exact)
                    HsU hs; hs.h = (_Float16)h;
                    hist[lane - H_SZ][t] = hs.s;       // f16 history for attention
                }
            }
            __atomic_store_n(&consumed, w + 1, __ATOMIC_RELEASE);
        }
    } else {
        // ---------------- producers: gx windows via f16 MFMA ----------------
        float bias[8];
#pragma unroll
        for (int nt = 0; nt < 8; ++nt)
            bias[nt] = b_ih[nt * 16 + m16] + b_hh[nt * 16 + m16];
        const float* xb = x + (size_t)b * T_SZ * I_SZ;

        for (int w = wave - 1; w < NWIN; w += 3) {
            const float* xrow = xb + (size_t)(w * 16 + m16) * I_SZ;
            f32x4 acc[8];
#pragma unroll
            for (int nt = 0; nt < 8; ++nt) acc[nt] = (f32x4){0.f, 0.f, 0.f, 0.f};

            for (int ks = 0; ks < 9; ++ks) {           // k = 0..287
                const int k0 = ks * 32 + quad * 8;
                f32x4 x0 = *(const f32x4*)(xrow + k0);
                f32x4 x1 = *(const f32x4*)(xrow + k0 + 4);
                FragH a;
                a.h[0] = (_Float16)x0[0]; a.h[1] = (_Float16)x0[1];
                a.h[2] = (_Float16)x0[2]; a.h[3] = (_Float16)x0[3];
                a.h[4] = (_Float16)x1[0]; a.h[5] = (_Float16)x1[1];
                a.h[6] = (_Float16)x1[2]; a.h[7] = (_Float16)x1[3];
#pragma unroll
                for (int nt = 0; nt < 8; ++nt) {
                    FragH bb;
                    bb.u4 = *(const uint4*)(W_ihH + (size_t)(nt * 16 + m16) * KPAD + k0);
                    acc[nt] = __builtin_amdgcn_mfma_f32_16x16x32_f16(a.v, bb.v, acc[nt], 0, 0, 0);
                }
            }
            {   // tail k = 288..299 (x predicated; W_ihH zero-padded to 320)
                FragH a;
#pragma unroll
                for (int jj = 0; jj < 8; ++jj) {
                    int k = 288 + quad * 8 + jj;
                    a.h[jj] = (k < I_SZ) ? (_Float16)xrow[k] : (_Float16)0.f;
                }
#pragma unroll
                for (int nt = 0; nt < 8; ++nt) {
                    FragH bb;
                    bb.u4 = *(const uint4*)(W_ihH + (size_t)(nt * 16 + m16) * KPAD + 288 + quad * 8);
                    acc[nt] = __builtin_amdgcn_mfma_f32_16x16x32_f16(a.v, bb.v, acc[nt], 0, 0, 0);
                }
            }
            // back-pressure: slot w%NBUF reusable once window w-NBUF consumed
            while (__atomic_load_n(&consumed, __ATOMIC_ACQUIRE) < w - (NBUF - 1))
                __builtin_amdgcn_s_sleep(8);
            // C/D: row(tl) = quad*4+r, col = nt*16+m16. Pack (col, col+64) f16 pair.
#pragma unroll
            for (int nt = 0; nt < 4; ++nt)
#pragma unroll
                for (int r = 0; r < 4; ++r) {
                    PkU p;
                    p.h[0] = (_Float16)(acc[nt][r]     + bias[nt]);
                    p.h[1] = (_Float16)(acc[nt + 4][r] + bias[nt + 4]);
                    gxbuf[w & (NBUF - 1)][quad * 4 + r][nt * 16 + m16] = p.u;
                }
            // in-order release
            while (__atomic_load_n(&produced, __ATOMIC_ACQUIRE) != w)
                __builtin_amdgcn_s_sleep(8);
            __atomic_store_n(&produced, w + 1, __ATOMIC_RELEASE);
        }
    }
    __syncthreads();   // hist complete

    // ---------------- attention: q = Ww@h, qk = h*q, fc = <qk,Wfc> ----------------
    float* region = out + B_SZ + (size_t)b * T_SZ * H_SZ;
    float fc_acc = 0.f;

    for (int st = wave; st < T_SZ / 16; st += 4) {
        const int s0 = st * 16;
        f32x4 acc0 = (f32x4){0.f,0.f,0.f,0.f};
        f32x4 acc1 = (f32x4){0.f,0.f,0.f,0.f};
        const _Float16* wwrow = WwH + (size_t)(s0 + m16) * T_SZ;

        for (int t0 = 0; t0 < T_SZ; t0 += 32) {
            FragH a, b0, b1;
            a.u4  = *(const uint4*)(wwrow + t0 + quad * 8);
            b0.u4 = *(const uint4*)&hist[m16][t0 + quad * 8];
            b1.u4 = *(const uint4*)&hist[16 + m16][t0 + quad * 8];
            acc0 = __builtin_amdgcn_mfma_f32_16x16x32_f16(a.v, b0.v, acc0, 0, 0, 0);
            acc1 = __builtin_amdgcn_mfma_f32_16x16x32_f16(a.v, b1.v, acc1, 0, 0, 0);
        }
#pragma unroll
        for (int r = 0; r < 4; ++r) {
            int s = s0 + quad * 4 + r;
            float bws = bw[s];
            HsU u0; u0.s = hist[m16][s];      float h0 = (float)u0.h;
            HsU u1; u1.s = hist[16 + m16][s]; float h1 = (float)u1.h;
            float q0 = acc0[r] + bws;
            float q1 = acc1[r] + bws;
            float qk0 = h0 * q0;
            float qk1 = h1 * q1;
            region[(size_t)s * H_SZ + m16]      = qk0;
            region[(size_t)s * H_SZ + 16 + m16] = qk1;
            fc_acc += qk0 * Wfc[s * H_SZ + m16];
            fc_acc += qk1 * Wfc[s * H_SZ + 16 + m16];
        }
    }

#pragma unroll
    for (int off = 32; off > 0; off >>= 1)
        fc_acc += __shfl_down(fc_acc, off, 64);
    if (lane == 0) red[wave] = fc_acc;
    __syncthreads();
    if (tid == 0) out[b] = red[0] + red[1] + red[2] + red[3] + bfc[0];
}

extern "C" void kernel_launch(void* const* d_in, const int* in_sizes, int n_in,
                              void* d_out, int out_size, void* d_ws, size_t ws_size,
                              hipStream_t stream) {
    const float* x    = (const float*)d_in[0];
    const float* W_ih = (const float*)d_in[1];
    const float* W_hh = (const float*)d_in[2];
    const float* b_ih = (const float*)d_in[3];
    const float* b_hh = (const float*)d_in[4];
    const float* Ww   = (const float*)d_in[5];
    const float* bw   = (const float*)d_in[6];
    const float* Wfc  = (const float*)d_in[7];
    const float* bfc  = (const float*)d_in[8];

    float* out = (float*)d_out;

    // ws: W_ihH f16 [128][320] = 81,920 B ; WwH f16 [800][800] = 1,280,000 B
    _Float16* W_ihH = (_Float16*)d_ws;
    _Float16* WwH   = (_Float16*)((char*)d_ws + (size_t)G_SZ * KPAD * 2);

    int prep_n = G_SZ * KPAD + T_SZ * T_SZ;
    k_prep<<<(prep_n + 255) / 256, 256, 0, stream>>>(W_ih, Ww, W_ihH, WwH);
    k_main<<<B_SZ, 256, 0, stream>>>(x, W_ihH, W_hh, b_ih, b_hh, WwH, bw, Wfc, bfc, out);
}